// Round 15
// baseline (986.374 us; speedup 1.0000x reference)
//
#include <hip/hip_runtime.h>

#define NROWS 50000
#define DIM   256
#define SHOPS 6
#define ROUNDS 4
#define EPSV  1e-5f
#define ND ((size_t)NROWS * DIM)
#define NB  196                              // ceil(NROWS/256)
#define EMAXR 32768                          // live rows = 31606 +- ~110
#define EMAXND ((size_t)EMAXR * DIM)

typedef _Float16 f16x8 __attribute__((ext_vector_type(8)));
typedef _Float16 f16x4 __attribute__((ext_vector_type(4)));
typedef float    f32x4 __attribute__((ext_vector_type(4)));

#define GLDS16(GP, LP) \
    __builtin_amdgcn_global_load_lds((const __attribute__((address_space(1))) unsigned*)(GP), \
                                     (__attribute__((address_space(3))) unsigned*)(LP), 16, 0, 0)

__device__ __forceinline__ int imin(int a, int b) { return a < b ? a : b; }

// ---------------------------------------------------------------------------
// 512-thread full-row msg GEMM (r14 structure) with 2-BUFFER pipeline:
// LDS 48KB -> 3 blocks/CU (24 waves, was 2 blocks/16 waves at 72KB).
// Per k-step: vmcnt(0); barrier; stage(t+1, (t+1)&1); compute(t&1).
// Buffer (t+1)&1 was consumed by compute(t-1) which precedes the barrier.
// ---------------------------------------------------------------------------
__global__ __launch_bounds__(512)
void gemm_p(const _Float16* __restrict__ A, const _Float16* __restrict__ WH,
            int s0, int s1, int nz, _Float16* __restrict__ C0,
            _Float16* __restrict__ CZ, int ctr0, int nwg,
            const int* __restrict__ LIVE, const int* __restrict__ Ecnt,
            int sbase)
{
    __shared__ char ldsb[2 * 24576];          // 48KB: per buf A 8KB + W 16KB

    // bijective XCD chunking (m204), z fastest within XCD, panel-spread bx
    const int bid = blockIdx.x;
    const int q   = nwg >> 3, r = nwg & 7;
    const int xcd = bid & 7,  ii = bid >> 3;
    const int g   = (xcd < r) ? xcd * (q + 1) + ii
                              : r * (q + 1) + (xcd - r) * q + ii;
    const int j   = g / nz;
    const size_t z = g - j * nz;
    int xp, jj;
    if (j < 7 * 49) { xp = j / 49; jj = j % 49; }
    else            { xp = 7; jj = j - 7 * 49; }
    const int bx = jj * 8 + xp;

    const int seg = sbase + (int)z;
    const int En  = (seg >= 0) ? Ecnt[seg] : NROWS;
    const int bm0 = bx * 128;
    if (bm0 >= En) return;
    const int* lvp = (seg >= 0) ? LIVE + (size_t)seg * NROWS : nullptr;

    const int tid = threadIdx.x;
    const int l   = tid & 63;
    const int w   = tid >> 6;                 // 0..7
    const int wm  = w & 1;
    const int wn  = w >> 1;                   // 0..3
    const int lr  = l & 15;
    const int sl  = l >> 4;

    const int wslot = (z == 0) ? s0 : s1 + (int)z;
    const char* Ab = (const char*)A;
    const char* Wb = (const char*)(WH + (size_t)wslot * (DIM * DIM));

    int arow, aslog, wr0, ws0, wr1, ws1;
    {
        int c = tid, row = c >> 2;
        aslog = (c & 3) ^ ((row >> 1) & 3);
        const int cl = imin(bm0 + row, En - 1);
        arow = lvp ? lvp[cl] : cl;
        ws0 = aslog; wr0 = row;
        c = tid + 512; row = c >> 2;
        ws1 = (c & 3) ^ ((row >> 1) & 3); wr1 = row;
    }

    f32x4 acc[4][4];
    #pragma unroll
    for (int mt = 0; mt < 4; ++mt)
        #pragma unroll
        for (int nt = 0; nt < 4; ++nt)
            acc[mt][nt] = (f32x4){0.f, 0.f, 0.f, 0.f};

    auto stage = [&](int step, int buf) {
        const int kt64 = step * 64;
        char* base = ldsb + buf * 24576;
        GLDS16(Ab + (size_t)arow * 512 + kt64 + aslog * 16, base + w * 1024);
        GLDS16(Wb + (size_t)wr0 * 512 + kt64 + ws0 * 16, base + 8192 + w * 1024);
        GLDS16(Wb + (size_t)wr1 * 512 + kt64 + ws1 * 16, base + 16384 + w * 1024);
    };

    auto compute = [&](int buf) {
        const char* base = ldsb + buf * 24576;
        f16x8 af[4], bf[4];
        #pragma unroll
        for (int mt = 0; mt < 4; ++mt) {
            const int row = wm * 64 + mt * 16 + lr;
            af[mt] = *(const f16x8*)(base + row * 64 + ((sl ^ ((row >> 1) & 3)) << 4));
        }
        #pragma unroll
        for (int nt = 0; nt < 4; ++nt) {
            const int row = wn * 64 + nt * 16 + lr;   // 0..255
            bf[nt] = *(const f16x8*)(base + 8192 + row * 64 + ((sl ^ ((row >> 1) & 3)) << 4));
        }
        #pragma unroll
        for (int mt = 0; mt < 4; ++mt)
            #pragma unroll
            for (int nt = 0; nt < 4; ++nt)
                acc[mt][nt] = __builtin_amdgcn_mfma_f32_16x16x32_f16(
                    af[mt], bf[nt], acc[mt][nt], 0, 0, 0);
    };

    stage(0, 0);
    #pragma unroll
    for (int t = 0; t < 8; ++t) {
        asm volatile("s_waitcnt vmcnt(0)" ::: "memory");   // stage(t) landed
        __builtin_amdgcn_s_barrier();
        __builtin_amdgcn_sched_barrier(0);
        if (t < 7) stage(t + 1, (t + 1) & 1);              // flies under compute(t)
        compute(t & 1);
    }

    // ---- epilogue: two 64x264 half-tiles, 4 x 16B stores/thread/half ----
    _Float16* et = (_Float16*)ldsb;           // [64][264] = 33792 B
    _Float16* Cb = (ctr0 && z == 0) ? C0 : CZ + (size_t)((int)z - ctr0) * EMAXND;
    #pragma unroll
    for (int half = 0; half < 2; ++half) {
        __syncthreads();
        if (wm == half) {
            #pragma unroll
            for (int mt = 0; mt < 4; ++mt)
                #pragma unroll
                for (int nt = 0; nt < 4; ++nt)
                    #pragma unroll
                    for (int jv = 0; jv < 4; ++jv) {
                        const int rl  = mt * 16 + sl * 4 + jv;   // 0..63
                        const int col = wn * 64 + nt * 16 + lr;  // 0..255
                        et[rl * 264 + col] = (_Float16)acc[mt][nt][jv];
                    }
        }
        __syncthreads();
        #pragma unroll
        for (int qq = 0; qq < 4; ++qq) {
            const int c   = qq * 512 + tid;   // 0..2047
            const int row = c >> 5;           // 0..63
            const int cc  = (c & 31) * 8;     // 0..248
            const int orow = bm0 + half * 64 + row;
            if (orow < En) {
                const f16x8 v = *(const f16x8*)(et + row * 264 + cc);
                *(f16x8*)(Cb + (size_t)orow * DIM + cc) = v;
            }
        }
    }
}

// ---------------------------------------------------------------------------
// Fused ctr2 GEMM + GroupNorm + residual + ReLU (unchanged from r13/r14).
// ---------------------------------------------------------------------------
__global__ __launch_bounds__(512)
void gemm_gn(const _Float16* __restrict__ A, const _Float16* __restrict__ WH,
             int wslot, const float* __restrict__ gw, const float* __restrict__ gb,
             float* __restrict__ X, _Float16* __restrict__ Xh, int writex)
{
    __shared__ char ldsb[3 * 24576 + 4096];
    float* sArr  = (float*)(ldsb + 73728);
    float* ssArr = sArr + 512;

    const int tid = threadIdx.x;
    const int l   = tid & 63;
    const int w   = tid >> 6;
    const int wm  = w & 1;
    const int wn  = w >> 1;
    const int bm0 = blockIdx.x * 128;
    const int lr  = l & 15;
    const int sl  = l >> 4;

    const char* Ab = (const char*)A;
    const char* Wb = (const char*)(WH + (size_t)wslot * (DIM * DIM));

    int arow, aslog, wr0, ws0, wr1, ws1;
    {
        int c = tid, row = c >> 2;
        aslog = (c & 3) ^ ((row >> 1) & 3);
        arow  = imin(bm0 + row, NROWS - 1);
        ws0 = aslog; wr0 = row;
        c = tid + 512; row = c >> 2;
        ws1 = (c & 3) ^ ((row >> 1) & 3); wr1 = row;
    }

    f32x4 acc[4][4];
    #pragma unroll
    for (int mt = 0; mt < 4; ++mt)
        #pragma unroll
        for (int nt = 0; nt < 4; ++nt)
            acc[mt][nt] = (f32x4){0.f, 0.f, 0.f, 0.f};

    auto stage = [&](int step, int buf) {
        const int kt64 = step * 64;
        char* base = ldsb + buf * 24576;
        GLDS16(Ab + (size_t)arow * 512 + kt64 + aslog * 16, base + w * 1024);
        GLDS16(Wb + (size_t)wr0 * 512 + kt64 + ws0 * 16, base + 8192 + w * 1024);
        GLDS16(Wb + (size_t)wr1 * 512 + kt64 + ws1 * 16, base + 16384 + w * 1024);
    };

    auto compute = [&](int buf) {
        const char* base = ldsb + buf * 24576;
        f16x8 af[4], bf[4];
        #pragma unroll
        for (int mt = 0; mt < 4; ++mt) {
            const int row = wm * 64 + mt * 16 + lr;
            af[mt] = *(const f16x8*)(base + row * 64 + ((sl ^ ((row >> 1) & 3)) << 4));
        }
        #pragma unroll
        for (int nt = 0; nt < 4; ++nt) {
            const int row = wn * 64 + nt * 16 + lr;
            bf[nt] = *(const f16x8*)(base + 8192 + row * 64 + ((sl ^ ((row >> 1) & 3)) << 4));
        }
        #pragma unroll
        for (int mt = 0; mt < 4; ++mt)
            #pragma unroll
            for (int nt = 0; nt < 4; ++nt)
                acc[mt][nt] = __builtin_amdgcn_mfma_f32_16x16x32_f16(
                    af[mt], bf[nt], acc[mt][nt], 0, 0, 0);
    };

    stage(0, 0);
    stage(1, 1);
    #pragma unroll
    for (int t = 0; t < 7; ++t) {
        asm volatile("s_waitcnt vmcnt(3)" ::: "memory");
        __builtin_amdgcn_s_barrier();
        __builtin_amdgcn_sched_barrier(0);
        if (t < 6) stage(t + 2, (t + 2) % 3);
        compute(t % 3);
    }
    asm volatile("s_waitcnt vmcnt(0)" ::: "memory");
    __builtin_amdgcn_s_barrier();
    __builtin_amdgcn_sched_barrier(0);
    compute(7 % 3);

    // ---- GN stats ----
    float sp[4][4], ssp[4][4];
    #pragma unroll
    for (int mt = 0; mt < 4; ++mt)
        #pragma unroll
        for (int jv = 0; jv < 4; ++jv) {
            float s = 0.f, ss = 0.f;
            #pragma unroll
            for (int nt = 0; nt < 4; ++nt) {
                const float v = acc[mt][nt][jv];
                s += v; ss += v * v;
            }
            sp[mt][jv] = s; ssp[mt][jv] = ss;
        }
    #pragma unroll
    for (int off = 1; off < 16; off <<= 1)
        #pragma unroll
        for (int mt = 0; mt < 4; ++mt)
            #pragma unroll
            for (int jv = 0; jv < 4; ++jv) {
                sp[mt][jv]  += __shfl_xor(sp[mt][jv], off);
                ssp[mt][jv] += __shfl_xor(ssp[mt][jv], off);
            }
    __syncthreads();
    if (lr == 0) {
        #pragma unroll
        for (int mt = 0; mt < 4; ++mt)
            #pragma unroll
            for (int jv = 0; jv < 4; ++jv) {
                const int row = wm * 64 + mt * 16 + sl * 4 + jv;
                sArr[wn * 128 + row]  = sp[mt][jv];
                ssArr[wn * 128 + row] = ssp[mt][jv];
            }
    }
    __syncthreads();
    float mv[4][4], iv[4][4];
    #pragma unroll
    for (int mt = 0; mt < 4; ++mt)
        #pragma unroll
        for (int jv = 0; jv < 4; ++jv) {
            const int row = wm * 64 + mt * 16 + sl * 4 + jv;
            const float S  = sArr[row] + sArr[128 + row] + sArr[256 + row] + sArr[384 + row];
            const float SS = ssArr[row] + ssArr[128 + row] + ssArr[256 + row] + ssArr[384 + row];
            const float m  = S * (1.0f / DIM);
            mv[mt][jv] = m;
            iv[mt][jv] = rsqrtf(SS * (1.0f / DIM) - m * m + EPSV);
        }
    float gwv[4], gbv[4];
    #pragma unroll
    for (int nt = 0; nt < 4; ++nt) {
        const int col = wn * 64 + nt * 16 + lr;
        gwv[nt] = gw[col]; gbv[nt] = gb[col];
    }

    _Float16* et = (_Float16*)ldsb;
    #pragma unroll
    for (int half = 0; half < 2; ++half) {
        __syncthreads();
        if (wm == half) {
            #pragma unroll
            for (int mt = 0; mt < 4; ++mt)
                #pragma unroll
                for (int nt = 0; nt < 4; ++nt)
                    #pragma unroll
                    for (int jv = 0; jv < 4; ++jv) {
                        const int rl  = mt * 16 + sl * 4 + jv;
                        const int col = wn * 64 + nt * 16 + lr;
                        et[rl * 264 + col] = (_Float16)((acc[mt][nt][jv] - mv[mt][jv])
                                                        * iv[mt][jv] * gwv[nt] + gbv[nt]);
                    }
        }
        __syncthreads();
        #pragma unroll
        for (int qq = 0; qq < 4; ++qq) {
            const int c   = qq * 512 + tid;
            const int row = c >> 5;
            const int cc  = (c & 31) * 8;
            const int orow = bm0 + half * 64 + row;
            if (orow < NROWS) {
                const f16x8 y = *(const f16x8*)(et + row * 264 + cc);
                const f16x8 rr = *(const f16x8*)(Xh + (size_t)orow * DIM + cc);
                float o[8];
                #pragma unroll
                for (int e = 0; e < 8; ++e)
                    o[e] = fmaxf((float)y[e] + (float)rr[e], 0.f);
                f16x8 oh;
                #pragma unroll
                for (int e = 0; e < 8; ++e) oh[e] = (_Float16)o[e];
                *(f16x8*)(Xh + (size_t)orow * DIM + cc) = oh;
                if (writex) {
                    float* xp = X + (size_t)orow * DIM + cc;
                    *(float4*)xp       = make_float4(o[0], o[1], o[2], o[3]);
                    *(float4*)(xp + 4) = make_float4(o[4], o[5], o[6], o[7]);
                }
            }
        }
    }
}

// ---------------------------------------------------------------------------
// Fused prep (unchanged)
// ---------------------------------------------------------------------------
__global__ __launch_bounds__(256)
void cvt_init(const float* __restrict__ lane, _Float16* __restrict__ Xh,
              const float* __restrict__ Wctr, const float* __restrict__ Wctr2,
              const float* __restrict__ Wpre, const float* __restrict__ Wsuc,
              _Float16* __restrict__ WH)
{
    const int bid = blockIdx.x;
    if (bid < 12500) {
        const size_t i4 = (size_t)bid * 256 + threadIdx.x;
        if (i4 >= ND / 4) return;
        const float4 v = *(const float4*)(lane + i4 * 4);
        f16x4 h;
        h[0] = (_Float16)v.x; h[1] = (_Float16)v.y;
        h[2] = (_Float16)v.z; h[3] = (_Float16)v.w;
        *(f16x4*)(Xh + i4 * 4) = h;
    } else {
        const size_t i4 = (size_t)(bid - 12500) * 256 + threadIdx.x;
        const size_t NT = (size_t)56 * DIM * DIM / 4;
        if (i4 >= NT) return;
        const size_t e = i4 * 4;
        const int slot = (int)(e >> 16);
        const int off  = (int)(e & 65535);
        const float* src;
        if (slot < 48) {
            const int r = slot / 12, s = slot % 12, k = s >> 1, dir = s & 1;
            src = (dir ? Wsuc : Wpre) + (((size_t)r * SHOPS + k) << 16) + off;
        } else if (slot < 52) {
            src = Wctr + ((size_t)(slot - 48) << 16) + off;
        } else {
            src = Wctr2 + ((size_t)(slot - 52) << 16) + off;
        }
        const float4 v = *(const float4*)src;
        f16x4 h;
        h[0] = (_Float16)v.x; h[1] = (_Float16)v.y;
        h[2] = (_Float16)v.z; h[3] = (_Float16)v.w;
        *(f16x4*)(WH + e) = h;
    }
}

__global__ __launch_bounds__(256)
void markcount(const int* __restrict__ pidx, const int* __restrict__ sidx,
               const int* __restrict__ nhp, const int* __restrict__ nhs,
               int* __restrict__ mark, int* __restrict__ counts,
               int* __restrict__ countsA)
{
    const int i = blockIdx.x * 256 + threadIdx.x;
    if (i >= NROWS) return;
    const int s = blockIdx.y;
    const int k = s >> 1, dir = s & 1;
    const int* gp  = (dir ? nhs  : nhp)  + k * NROWS;
    const int* scp = (dir ? pidx : sidx) + k * NROWS;
    mark[(size_t)s * NROWS + gp[i]] = 1;
    const int dst = scp[i];
    atomicAdd(&counts[dst], 1);
    if (s < 6) atomicAdd(&countsA[dst], 1);
}

__global__ __launch_bounds__(256)
void pscan1(const int* __restrict__ mark, const int* __restrict__ counts,
            int* __restrict__ mrank, int* __restrict__ msum,
            int* __restrict__ offs, int* __restrict__ bsum)
{
    __shared__ int wsum[4];
    const int y = blockIdx.y;
    const int tid = threadIdx.x, lane = tid & 63, wv = tid >> 6;
    const int i = blockIdx.x * 256 + tid;
    const int c = (i < NROWS) ? ((y < 12) ? mark[(size_t)y * NROWS + i] : counts[i]) : 0;
    int v = c;
    #pragma unroll
    for (int off = 1; off < 64; off <<= 1) {
        const int t = __shfl_up(v, off);
        if (lane >= off) v += t;
    }
    if (lane == 63) wsum[wv] = v;
    __syncthreads();
    int add = 0;
    for (int w = 0; w < wv; ++w) add += wsum[w];
    const int excl = add + v - c;
    if (i < NROWS) {
        if (y < 12) mrank[(size_t)y * NROWS + i] = excl;
        else        offs[i] = excl;
    }
    if (tid == 255) {
        const int tot = wsum[0] + wsum[1] + wsum[2] + wsum[3];
        if (y < 12) msum[y * 256 + blockIdx.x] = tot;
        else        bsum[blockIdx.x] = tot;
    }
}

__global__ __launch_bounds__(256)
void pscan2(const int* __restrict__ msum, const int* __restrict__ bsum,
            int* __restrict__ mbpre, int* __restrict__ bpre,
            int* __restrict__ Ecnt)
{
    __shared__ int wsum[4];
    const int y = blockIdx.x;
    const int tid = threadIdx.x, lane = tid & 63, wv = tid >> 6;
    const int c = (tid < NB) ? ((y < 12) ? msum[y * 256 + tid] : bsum[tid]) : 0;
    int v = c;
    #pragma unroll
    for (int off = 1; off < 64; off <<= 1) {
        const int t = __shfl_up(v, off);
        if (lane >= off) v += t;
    }
    if (lane == 63) wsum[wv] = v;
    __syncthreads();
    int add = 0;
    for (int w = 0; w < wv; ++w) add += wsum[w];
    if (tid < NB) {
        if (y < 12) mbpre[y * 256 + tid] = add + v - c;
        else        bpre[tid] = add + v - c;
    }
    if (tid == 0 && y < 12)
        Ecnt[y] = wsum[0] + wsum[1] + wsum[2] + wsum[3];
}

__global__ __launch_bounds__(256)
void pscan3(const int* __restrict__ mark, int* __restrict__ mrank,
            const int* __restrict__ mbpre, int* __restrict__ live,
            int* __restrict__ offs, const int* __restrict__ bpre,
            const int* __restrict__ countsA, int* __restrict__ cursorA,
            int* __restrict__ cursorB, int* __restrict__ mid)
{
    const int i = blockIdx.x * 256 + threadIdx.x;
    const int y = blockIdx.y;
    if (y < 12) {
        if (i >= NROWS) return;
        const size_t o = (size_t)y * NROWS + i;
        const int rk = mrank[o] + mbpre[y * 256 + blockIdx.x];
        mrank[o] = rk;
        if (mark[o]) live[(size_t)y * NROWS + rk] = i;
    } else {
        if (i < NROWS) {
            const int v = offs[i] + bpre[blockIdx.x];
            offs[i] = v;
            cursorA[i] = v;
            const int m = v + countsA[i];
            mid[i] = m;
            cursorB[i] = m;
        }
        if (i == 0) offs[NROWS] = 12 * NROWS;
    }
}

__global__ __launch_bounds__(256)
void fill_kernel(const int* __restrict__ pidx, const int* __restrict__ sidx,
                 const int* __restrict__ nhp, const int* __restrict__ nhs,
                 const int* __restrict__ mrank,
                 int* __restrict__ cursorA, int* __restrict__ cursorB,
                 int* __restrict__ entries)
{
    const int i = blockIdx.x * 256 + threadIdx.x;
    if (i >= NROWS) return;
    const int s = blockIdx.y;
    const int k = s >> 1, dir = s & 1;
    const int* scp = (dir ? pidx : sidx) + k * NROWS;
    const int* gp  = (dir ? nhs  : nhp)  + k * NROWS;
    const int dst = scp[i];
    const int pos = (s < 6) ? atomicAdd(&cursorA[dst], 1)
                            : atomicAdd(&cursorB[dst], 1);
    entries[pos] = (s << 16) | mrank[(size_t)s * NROWS + gp[i]];
}

// ---------------------------------------------------------------------------
// combine (unchanged): prefetch-pipelined gather, compacted slots.
// ---------------------------------------------------------------------------
#define PF 20
template<int FIRST, int LAST>
__global__ __launch_bounds__(256)
void combine_f16(const _Float16* __restrict__ YC, _Float16* __restrict__ TEMP16,
                 const _Float16* __restrict__ YB,
                 const int* __restrict__ offsets, const int* __restrict__ mid,
                 const int* __restrict__ entries,
                 int c0, int half,
                 const float* __restrict__ gw, const float* __restrict__ gb,
                 _Float16* __restrict__ Hh)
{
    const int lane = threadIdx.x & 63;
    const int wv   = threadIdx.x >> 6;
    const int r    = blockIdx.x * 4 + wv;
    if (r >= NROWS) return;
    const size_t rowoff = (size_t)r * DIM + lane * 4;

    const f16x4 ivv = FIRST ? *(const f16x4*)(YC + rowoff)
                            : *(const f16x4*)(TEMP16 + rowoff);
    float4 acc;
    acc.x = (float)ivv[0]; acc.y = (float)ivv[1];
    acc.z = (float)ivv[2]; acc.w = (float)ivv[3];

    int e0, e1;
    if (half == 0)      { e0 = offsets[r]; e1 = mid[r]; }
    else if (half == 1) { e0 = mid[r];     e1 = offsets[r + 1]; }
    else                { e0 = offsets[r]; e1 = offsets[r + 1]; }

    const int n  = e1 - e0;
    const int nf = n < PF ? n : PF;
    f16x4 buf[PF];
    #pragma unroll
    for (int t = 0; t < PF; ++t) {
        if (t < nf) {
            const int ent = entries[e0 + t];
            buf[t] = *(const f16x4*)(YB + (size_t)((ent >> 16) - c0) * EMAXND
                                     + (size_t)(ent & 0xFFFF) * DIM + lane * 4);
        }
    }
    #pragma unroll
    for (int t = 0; t < PF; ++t) {
        if (t < nf) {
            acc.x += (float)buf[t][0]; acc.y += (float)buf[t][1];
            acc.z += (float)buf[t][2]; acc.w += (float)buf[t][3];
        }
    }
    for (int e = e0 + nf; e < e1; ++e) {
        const int ent = entries[e];
        const f16x4 yv = *(const f16x4*)(YB + (size_t)((ent >> 16) - c0) * EMAXND
                                         + (size_t)(ent & 0xFFFF) * DIM + lane * 4);
        acc.x += (float)yv[0]; acc.y += (float)yv[1];
        acc.z += (float)yv[2]; acc.w += (float)yv[3];
    }

    if (LAST) {
        float s  = acc.x + acc.y + acc.z + acc.w;
        float ss = acc.x * acc.x + acc.y * acc.y + acc.z * acc.z + acc.w * acc.w;
        #pragma unroll
        for (int off = 32; off >= 1; off >>= 1) {
            s  += __shfl_xor(s, off);
            ss += __shfl_xor(ss, off);
        }
        const float m   = s * (1.0f / DIM);
        const float var = ss * (1.0f / DIM) - m * m;
        const float inv = rsqrtf(var + EPSV);
        const float4 wv4 = *(const float4*)(gw + lane * 4);
        const float4 bv4 = *(const float4*)(gb + lane * 4);
        f16x4 o;
        o[0] = (_Float16)fmaxf((acc.x - m) * inv * wv4.x + bv4.x, 0.f);
        o[1] = (_Float16)fmaxf((acc.y - m) * inv * wv4.y + bv4.y, 0.f);
        o[2] = (_Float16)fmaxf((acc.z - m) * inv * wv4.z + bv4.z, 0.f);
        o[3] = (_Float16)fmaxf((acc.w - m) * inv * wv4.w + bv4.w, 0.f);
        *(f16x4*)(Hh + rowoff) = o;
    } else {
        f16x4 o;
        o[0] = (_Float16)acc.x; o[1] = (_Float16)acc.y;
        o[2] = (_Float16)acc.z; o[3] = (_Float16)acc.w;
        *(f16x4*)(TEMP16 + rowoff) = o;
    }
}

// ---------------------------------------------------------------------------
extern "C" void kernel_launch(void* const* d_in, const int* in_sizes, int n_in,
                              void* d_out, int out_size, void* d_ws, size_t ws_size,
                              hipStream_t stream)
{
    const float* lane   = (const float*)d_in[0];
    const float* W_ctr  = (const float*)d_in[1];
    const float* norm_w = (const float*)d_in[2];
    const float* norm_b = (const float*)d_in[3];
    const float* W_ctr2 = (const float*)d_in[4];
    const float* c2w    = (const float*)d_in[5];
    const float* c2b    = (const float*)d_in[6];
    const float* W_pre  = (const float*)d_in[7];
    const float* W_suc  = (const float*)d_in[8];
    const int*   pidx   = (const int*)d_in[9];
    const int*   sidx   = (const int*)d_in[10];
    const int*   nhp    = (const int*)d_in[11];
    const int*   nhs    = (const int*)d_in[12];

    float* X = (float*)d_out;
    _Float16* YC = (_Float16*)d_out;          // ctr slot lives in d_out

    // ---- workspace layout ----
    char* p = (char*)d_ws;
    int* counts  = (int*)p; p += (size_t)NROWS * 4;
    int* countsA = (int*)p; p += (size_t)NROWS * 4;
    int* offsets = (int*)p; p += (size_t)(NROWS + 4) * 4;
    int* mid     = (int*)p; p += (size_t)NROWS * 4;
    int* cursorA = (int*)p; p += (size_t)NROWS * 4;
    int* cursorB = (int*)p; p += (size_t)NROWS * 4;
    int* bsum    = (int*)p; p += 256 * 4;
    int* bpre    = (int*)p; p += 256 * 4;
    int* msum    = (int*)p; p += 12 * 256 * 4;
    int* mbpre   = (int*)p; p += 12 * 256 * 4;
    int* Ecnt    = (int*)p; p += 16 * 4;
    int* entries = (int*)p; p += (size_t)12 * NROWS * 4;
    int* LIVE    = (int*)p; p += (size_t)12 * NROWS * 4;
    p = (char*)(((uintptr_t)p + 15) & ~(uintptr_t)15);
    _Float16* Xh = (_Float16*)p; p += ND * 2;
    _Float16* Hh = (_Float16*)p; p += ND * 2;
    _Float16* WH = (_Float16*)p; p += (size_t)56 * DIM * DIM * 2;
    p = (char*)(((uintptr_t)p + 255) & ~(uintptr_t)255);
    char* area = p;

    const size_t areaB = ws_size - (size_t)(area - (char*)d_ws);
    const size_t slotb = EMAXND * 2;
    int CH;
    _Float16 *T16, *YBUF;
    if (areaB >= 12 * slotb) {
        CH = 12;
        YBUF = (_Float16*)area;
        T16 = Hh;
    } else {
        CH = 6;
        T16 = (_Float16*)area;
        YBUF = T16 + ND;
    }

    int* mark  = (int*)area;                  // prep-only aliases
    int* mrank = mark + (size_t)12 * NROWS;

    const dim3 blk(256);
    const int  gnBlocks = (NROWS + 3) / 4;

    // one-time prep
    cvt_init<<<16084, blk, 0, stream>>>(lane, Xh, W_ctr, W_ctr2, W_pre, W_suc, WH);
    hipMemsetAsync(counts, 0, 2 * NROWS * sizeof(int), stream);
    hipMemsetAsync(mark, 0, (size_t)12 * NROWS * sizeof(int), stream);
    markcount<<<dim3(NB, 12), blk, 0, stream>>>(pidx, sidx, nhp, nhs,
                                                mark, counts, countsA);
    pscan1<<<dim3(NB, 13), blk, 0, stream>>>(mark, counts, mrank, msum, offsets, bsum);
    pscan2<<<13, blk, 0, stream>>>(msum, bsum, mbpre, bpre, Ecnt);
    pscan3<<<dim3(NB, 13), blk, 0, stream>>>(mark, mrank, mbpre, LIVE,
                                             offsets, bpre, countsA,
                                             cursorA, cursorB, mid);
    fill_kernel<<<dim3(NB, 12), blk, 0, stream>>>(pidx, sidx, nhp, nhs, mrank,
                                                  cursorA, cursorB, entries);

    for (int i = 0; i < ROUNDS; ++i) {
        if (CH == 12) {
            const int nwg = 391 * 13;
            gemm_p<<<dim3(nwg), 512, 0, stream>>>(Xh, WH, 48 + i, i * 12 - 1,
                                                  13, YC, YBUF, 1, nwg,
                                                  LIVE, Ecnt, -1);
            combine_f16<1, 1><<<gnBlocks, blk, 0, stream>>>(YC, T16, YBUF,
                offsets, mid, entries, 0, -1,
                norm_w + i * DIM, norm_b + i * DIM, Hh);
        } else {
            for (int c0 = 0; c0 < 12; c0 += 6) {
                const bool first = (c0 == 0);
                const int ctr0  = first ? 1 : 0;
                const int slots = 6 + ctr0;
                const int nwg   = 391 * slots;
                gemm_p<<<dim3(nwg), 512, 0, stream>>>(
                    Xh, WH, first ? (48 + i) : (i * 12 + c0), i * 12 + c0 - ctr0,
                    slots, YC, YBUF, ctr0, nwg, LIVE, Ecnt, c0 - ctr0);
                if (first)
                    combine_f16<1, 0><<<gnBlocks, blk, 0, stream>>>(YC, T16, YBUF,
                        offsets, mid, entries, c0, 0,
                        norm_w + i * DIM, norm_b + i * DIM, Hh);
                else
                    combine_f16<0, 1><<<gnBlocks, blk, 0, stream>>>(YC, T16, YBUF,
                        offsets, mid, entries, c0, 1,
                        norm_w + i * DIM, norm_b + i * DIM, Hh);
            }
        }
        gemm_gn<<<391, 512, 0, stream>>>(Hh, WH, 52 + i, c2w + i * DIM,
                                         c2b + i * DIM, X, Xh,
                                         (i == ROUNDS - 1) ? 1 : 0);
    }
}

// Round 16
// 947.251 us; speedup vs baseline: 1.0413x; 1.0413x over previous
//
#include <hip/hip_runtime.h>

#define NROWS 50000
#define DIM   256
#define SHOPS 6
#define ROUNDS 4
#define EPSV  1e-5f
#define ND ((size_t)NROWS * DIM)
#define NB  196                              // ceil(NROWS/256)
#define EMAXR 32768                          // live rows = 31606 +- ~110
#define EMAXND ((size_t)EMAXR * DIM)

typedef _Float16 f16x8 __attribute__((ext_vector_type(8)));
typedef _Float16 f16x4 __attribute__((ext_vector_type(4)));
typedef float    f32x4 __attribute__((ext_vector_type(4)));

#define GLDS16(GP, LP) \
    __builtin_amdgcn_global_load_lds((const __attribute__((address_space(1))) unsigned*)(GP), \
                                     (__attribute__((address_space(3))) unsigned*)(LP), 16, 0, 0)

__device__ __forceinline__ int imin(int a, int b) { return a < b ? a : b; }

// ---------------------------------------------------------------------------
// Pipelined fp16 MFMA GEMM (r13 best-measured config): 256 thr, tile 128x128,
// 3-buf counted-vmcnt(4), panel-spread XCD swizzle, 64B-row XOR swizzle,
// LDS-transposed epilogue. A-side gather via LIVE, compacted output.
// ---------------------------------------------------------------------------
__global__ __launch_bounds__(256)
void gemm_p(const _Float16* __restrict__ A, const _Float16* __restrict__ WH,
            int s0, int s1, int nz, _Float16* __restrict__ C0,
            _Float16* __restrict__ CZ, int ctr0, int nwg,
            const int* __restrict__ LIVE, const int* __restrict__ Ecnt,
            int sbase)
{
    __shared__ _Float16 lds[3][8192];        // 48KB
    char* ldsb = (char*)lds;

    const int bid = blockIdx.x;
    const int q   = nwg >> 3, r = nwg & 7;
    const int xcd = bid & 7,  ii = bid >> 3;
    const int g   = (xcd < r) ? xcd * (q + 1) + ii
                              : r * (q + 1) + (xcd - r) * q + ii;
    const int j   = g / (2 * nz);
    const int sub = g - j * 2 * nz;
    const int by  = sub & 1;
    const size_t z = sub >> 1;
    int xp, jj;
    if (j < 7 * 49) { xp = j / 49; jj = j % 49; }
    else            { xp = 7; jj = j - 7 * 49; }
    const int bx = jj * 8 + xp;

    const int seg = sbase + (int)z;
    const int En  = (seg >= 0) ? Ecnt[seg] : NROWS;
    const int bm0 = bx * 128;
    if (bm0 >= En) return;
    const int* lvp = (seg >= 0) ? LIVE + (size_t)seg * NROWS : nullptr;

    const int tid = threadIdx.x;
    const int l   = tid & 63;
    const int w   = tid >> 6;
    const int wm  = w & 1;
    const int wn  = w >> 1;
    const int bn0 = by * 128;
    const int lr  = l & 15;
    const int sl  = l >> 4;

    const int wslot = (z == 0) ? s0 : s1 + (int)z;
    const char* Ab = (const char*)A;
    const char* Wb = (const char*)(WH + (size_t)wslot * (DIM * DIM));

    int arow[2], slog[2], wrow[2];
    #pragma unroll
    for (int qq = 0; qq < 2; ++qq) {
        const int c   = (w * 2 + qq) * 64 + l;
        const int row = c >> 2;
        slog[qq] = (c & 3) ^ ((row >> 1) & 3);
        const int cl = imin(bm0 + row, En - 1);
        arow[qq] = lvp ? lvp[cl] : cl;
        wrow[qq] = bn0 + row;
    }

    f32x4 acc[4][4];
    #pragma unroll
    for (int mt = 0; mt < 4; ++mt)
        #pragma unroll
        for (int nt = 0; nt < 4; ++nt)
            acc[mt][nt] = (f32x4){0.f, 0.f, 0.f, 0.f};

    auto stage = [&](int step, int buf) {
        const int kt64 = step * 64;
        char* base = ldsb + buf * 16384;
        #pragma unroll
        for (int qq = 0; qq < 2; ++qq) {
            GLDS16(Ab + (size_t)arow[qq] * 512 + kt64 + slog[qq] * 16,
                   base + (w * 2 + qq) * 1024);
            GLDS16(Wb + (size_t)wrow[qq] * 512 + kt64 + slog[qq] * 16,
                   base + 8192 + (w * 2 + qq) * 1024);
        }
    };

    auto compute = [&](int buf) {
        const char* base = ldsb + buf * 16384;
        f16x8 af[4], bf[4];
        #pragma unroll
        for (int mt = 0; mt < 4; ++mt) {
            const int row = wm * 64 + mt * 16 + lr;
            af[mt] = *(const f16x8*)(base + row * 64 + ((sl ^ ((row >> 1) & 3)) << 4));
        }
        #pragma unroll
        for (int nt = 0; nt < 4; ++nt) {
            const int row = wn * 64 + nt * 16 + lr;
            bf[nt] = *(const f16x8*)(base + 8192 + row * 64 + ((sl ^ ((row >> 1) & 3)) << 4));
        }
        #pragma unroll
        for (int mt = 0; mt < 4; ++mt)
            #pragma unroll
            for (int nt = 0; nt < 4; ++nt)
                acc[mt][nt] = __builtin_amdgcn_mfma_f32_16x16x32_f16(
                    af[mt], bf[nt], acc[mt][nt], 0, 0, 0);
    };

    stage(0, 0);
    stage(1, 1);
    #pragma unroll
    for (int t = 0; t < 7; ++t) {
        asm volatile("s_waitcnt vmcnt(4)" ::: "memory");
        __builtin_amdgcn_s_barrier();
        __builtin_amdgcn_sched_barrier(0);
        if (t < 6) stage(t + 2, (t + 2) % 3);
        compute(t % 3);
    }
    asm volatile("s_waitcnt vmcnt(0)" ::: "memory");
    __builtin_amdgcn_s_barrier();
    __builtin_amdgcn_sched_barrier(0);
    compute(7 % 3);

    __syncthreads();
    _Float16* et = (_Float16*)ldsb;           // [128][136]
    #pragma unroll
    for (int mt = 0; mt < 4; ++mt)
        #pragma unroll
        for (int nt = 0; nt < 4; ++nt)
            #pragma unroll
            for (int jv = 0; jv < 4; ++jv) {
                const int row = wm * 64 + mt * 16 + sl * 4 + jv;
                const int col = wn * 64 + nt * 16 + lr;
                et[row * 136 + col] = (_Float16)acc[mt][nt][jv];
            }
    __syncthreads();
    _Float16* Cb = (ctr0 && z == 0) ? C0 : CZ + (size_t)((int)z - ctr0) * EMAXND;
    #pragma unroll
    for (int qq = 0; qq < 8; ++qq) {
        const int c   = qq * 256 + tid;
        const int row = c >> 4;
        const int cc  = (c & 15) * 8;
        const int orow = bm0 + row;
        if (orow < En) {
            const f16x8 v = *(const f16x8*)(et + row * 136 + cc);
            *(f16x8*)(Cb + (size_t)orow * DIM + bn0 + cc) = v;
        }
    }
}

// ---------------------------------------------------------------------------
// Fused ctr2 GEMM + GroupNorm + residual + ReLU (r13 config, 3-buf).
// ---------------------------------------------------------------------------
__global__ __launch_bounds__(512)
void gemm_gn(const _Float16* __restrict__ A, const _Float16* __restrict__ WH,
             int wslot, const float* __restrict__ gw, const float* __restrict__ gb,
             float* __restrict__ X, _Float16* __restrict__ Xh, int writex)
{
    __shared__ char ldsb[3 * 24576 + 4096];
    float* sArr  = (float*)(ldsb + 73728);
    float* ssArr = sArr + 512;

    const int tid = threadIdx.x;
    const int l   = tid & 63;
    const int w   = tid >> 6;
    const int wm  = w & 1;
    const int wn  = w >> 1;
    const int bm0 = blockIdx.x * 128;
    const int lr  = l & 15;
    const int sl  = l >> 4;

    const char* Ab = (const char*)A;
    const char* Wb = (const char*)(WH + (size_t)wslot * (DIM * DIM));

    int arow, aslog, wr0, ws0, wr1, ws1;
    {
        int c = tid, row = c >> 2;
        aslog = (c & 3) ^ ((row >> 1) & 3);
        arow  = imin(bm0 + row, NROWS - 1);
        ws0 = aslog; wr0 = row;
        c = tid + 512; row = c >> 2;
        ws1 = (c & 3) ^ ((row >> 1) & 3); wr1 = row;
    }

    f32x4 acc[4][4];
    #pragma unroll
    for (int mt = 0; mt < 4; ++mt)
        #pragma unroll
        for (int nt = 0; nt < 4; ++nt)
            acc[mt][nt] = (f32x4){0.f, 0.f, 0.f, 0.f};

    auto stage = [&](int step, int buf) {
        const int kt64 = step * 64;
        char* base = ldsb + buf * 24576;
        GLDS16(Ab + (size_t)arow * 512 + kt64 + aslog * 16, base + w * 1024);
        GLDS16(Wb + (size_t)wr0 * 512 + kt64 + ws0 * 16, base + 8192 + w * 1024);
        GLDS16(Wb + (size_t)wr1 * 512 + kt64 + ws1 * 16, base + 16384 + w * 1024);
    };

    auto compute = [&](int buf) {
        const char* base = ldsb + buf * 24576;
        f16x8 af[4], bf[4];
        #pragma unroll
        for (int mt = 0; mt < 4; ++mt) {
            const int row = wm * 64 + mt * 16 + lr;
            af[mt] = *(const f16x8*)(base + row * 64 + ((sl ^ ((row >> 1) & 3)) << 4));
        }
        #pragma unroll
        for (int nt = 0; nt < 4; ++nt) {
            const int row = wn * 64 + nt * 16 + lr;
            bf[nt] = *(const f16x8*)(base + 8192 + row * 64 + ((sl ^ ((row >> 1) & 3)) << 4));
        }
        #pragma unroll
        for (int mt = 0; mt < 4; ++mt)
            #pragma unroll
            for (int nt = 0; nt < 4; ++nt)
                acc[mt][nt] = __builtin_amdgcn_mfma_f32_16x16x32_f16(
                    af[mt], bf[nt], acc[mt][nt], 0, 0, 0);
    };

    stage(0, 0);
    stage(1, 1);
    #pragma unroll
    for (int t = 0; t < 7; ++t) {
        asm volatile("s_waitcnt vmcnt(3)" ::: "memory");
        __builtin_amdgcn_s_barrier();
        __builtin_amdgcn_sched_barrier(0);
        if (t < 6) stage(t + 2, (t + 2) % 3);
        compute(t % 3);
    }
    asm volatile("s_waitcnt vmcnt(0)" ::: "memory");
    __builtin_amdgcn_s_barrier();
    __builtin_amdgcn_sched_barrier(0);
    compute(7 % 3);

    // ---- GN stats ----
    float sp[4][4], ssp[4][4];
    #pragma unroll
    for (int mt = 0; mt < 4; ++mt)
        #pragma unroll
        for (int jv = 0; jv < 4; ++jv) {
            float s = 0.f, ss = 0.f;
            #pragma unroll
            for (int nt = 0; nt < 4; ++nt) {
                const float v = acc[mt][nt][jv];
                s += v; ss += v * v;
            }
            sp[mt][jv] = s; ssp[mt][jv] = ss;
        }
    #pragma unroll
    for (int off = 1; off < 16; off <<= 1)
        #pragma unroll
        for (int mt = 0; mt < 4; ++mt)
            #pragma unroll
            for (int jv = 0; jv < 4; ++jv) {
                sp[mt][jv]  += __shfl_xor(sp[mt][jv], off);
                ssp[mt][jv] += __shfl_xor(ssp[mt][jv], off);
            }
    __syncthreads();
    if (lr == 0) {
        #pragma unroll
        for (int mt = 0; mt < 4; ++mt)
            #pragma unroll
            for (int jv = 0; jv < 4; ++jv) {
                const int row = wm * 64 + mt * 16 + sl * 4 + jv;
                sArr[wn * 128 + row]  = sp[mt][jv];
                ssArr[wn * 128 + row] = ssp[mt][jv];
            }
    }
    __syncthreads();
    float mv[4][4], iv[4][4];
    #pragma unroll
    for (int mt = 0; mt < 4; ++mt)
        #pragma unroll
        for (int jv = 0; jv < 4; ++jv) {
            const int row = wm * 64 + mt * 16 + sl * 4 + jv;
            const float S  = sArr[row] + sArr[128 + row] + sArr[256 + row] + sArr[384 + row];
            const float SS = ssArr[row] + ssArr[128 + row] + ssArr[256 + row] + ssArr[384 + row];
            const float m  = S * (1.0f / DIM);
            mv[mt][jv] = m;
            iv[mt][jv] = rsqrtf(SS * (1.0f / DIM) - m * m + EPSV);
        }
    float gwv[4], gbv[4];
    #pragma unroll
    for (int nt = 0; nt < 4; ++nt) {
        const int col = wn * 64 + nt * 16 + lr;
        gwv[nt] = gw[col]; gbv[nt] = gb[col];
    }

    _Float16* et = (_Float16*)ldsb;
    #pragma unroll
    for (int half = 0; half < 2; ++half) {
        __syncthreads();
        if (wm == half) {
            #pragma unroll
            for (int mt = 0; mt < 4; ++mt)
                #pragma unroll
                for (int nt = 0; nt < 4; ++nt)
                    #pragma unroll
                    for (int jv = 0; jv < 4; ++jv) {
                        const int rl  = mt * 16 + sl * 4 + jv;
                        const int col = wn * 64 + nt * 16 + lr;
                        et[rl * 264 + col] = (_Float16)((acc[mt][nt][jv] - mv[mt][jv])
                                                        * iv[mt][jv] * gwv[nt] + gbv[nt]);
                    }
        }
        __syncthreads();
        #pragma unroll
        for (int qq = 0; qq < 4; ++qq) {
            const int c   = qq * 512 + tid;
            const int row = c >> 5;
            const int cc  = (c & 31) * 8;
            const int orow = bm0 + half * 64 + row;
            if (orow < NROWS) {
                const f16x8 y = *(const f16x8*)(et + row * 264 + cc);
                const f16x8 rr = *(const f16x8*)(Xh + (size_t)orow * DIM + cc);
                float o[8];
                #pragma unroll
                for (int e = 0; e < 8; ++e)
                    o[e] = fmaxf((float)y[e] + (float)rr[e], 0.f);
                f16x8 oh;
                #pragma unroll
                for (int e = 0; e < 8; ++e) oh[e] = (_Float16)o[e];
                *(f16x8*)(Xh + (size_t)orow * DIM + cc) = oh;
                if (writex) {
                    float* xp = X + (size_t)orow * DIM + cc;
                    *(float4*)xp       = make_float4(o[0], o[1], o[2], o[3]);
                    *(float4*)(xp + 4) = make_float4(o[4], o[5], o[6], o[7]);
                }
            }
        }
    }
}

// ---------------------------------------------------------------------------
// Fused prep (r13)
// ---------------------------------------------------------------------------
__global__ __launch_bounds__(256)
void cvt_init(const float* __restrict__ lane, _Float16* __restrict__ Xh,
              const float* __restrict__ Wctr, const float* __restrict__ Wctr2,
              const float* __restrict__ Wpre, const float* __restrict__ Wsuc,
              _Float16* __restrict__ WH)
{
    const int bid = blockIdx.x;
    if (bid < 12500) {
        const size_t i4 = (size_t)bid * 256 + threadIdx.x;
        if (i4 >= ND / 4) return;
        const float4 v = *(const float4*)(lane + i4 * 4);
        f16x4 h;
        h[0] = (_Float16)v.x; h[1] = (_Float16)v.y;
        h[2] = (_Float16)v.z; h[3] = (_Float16)v.w;
        *(f16x4*)(Xh + i4 * 4) = h;
    } else {
        const size_t i4 = (size_t)(bid - 12500) * 256 + threadIdx.x;
        const size_t NT = (size_t)56 * DIM * DIM / 4;
        if (i4 >= NT) return;
        const size_t e = i4 * 4;
        const int slot = (int)(e >> 16);
        const int off  = (int)(e & 65535);
        const float* src;
        if (slot < 48) {
            const int r = slot / 12, s = slot % 12, k = s >> 1, dir = s & 1;
            src = (dir ? Wsuc : Wpre) + (((size_t)r * SHOPS + k) << 16) + off;
        } else if (slot < 52) {
            src = Wctr + ((size_t)(slot - 48) << 16) + off;
        } else {
            src = Wctr2 + ((size_t)(slot - 52) << 16) + off;
        }
        const float4 v = *(const float4*)src;
        f16x4 h;
        h[0] = (_Float16)v.x; h[1] = (_Float16)v.y;
        h[2] = (_Float16)v.z; h[3] = (_Float16)v.w;
        *(f16x4*)(WH + e) = h;
    }
}

__global__ __launch_bounds__(256)
void markcount(const int* __restrict__ pidx, const int* __restrict__ sidx,
               const int* __restrict__ nhp, const int* __restrict__ nhs,
               int* __restrict__ mark, int* __restrict__ counts,
               int* __restrict__ countsA)
{
    const int i = blockIdx.x * 256 + threadIdx.x;
    if (i >= NROWS) return;
    const int s = blockIdx.y;
    const int k = s >> 1, dir = s & 1;
    const int* gp  = (dir ? nhs  : nhp)  + k * NROWS;
    const int* scp = (dir ? pidx : sidx) + k * NROWS;
    mark[(size_t)s * NROWS + gp[i]] = 1;
    const int dst = scp[i];
    atomicAdd(&counts[dst], 1);
    if (s < 6) atomicAdd(&countsA[dst], 1);
}

__global__ __launch_bounds__(256)
void pscan1(const int* __restrict__ mark, const int* __restrict__ counts,
            int* __restrict__ mrank, int* __restrict__ msum,
            int* __restrict__ offs, int* __restrict__ bsum)
{
    __shared__ int wsum[4];
    const int y = blockIdx.y;
    const int tid = threadIdx.x, lane = tid & 63, wv = tid >> 6;
    const int i = blockIdx.x * 256 + tid;
    const int c = (i < NROWS) ? ((y < 12) ? mark[(size_t)y * NROWS + i] : counts[i]) : 0;
    int v = c;
    #pragma unroll
    for (int off = 1; off < 64; off <<= 1) {
        const int t = __shfl_up(v, off);
        if (lane >= off) v += t;
    }
    if (lane == 63) wsum[wv] = v;
    __syncthreads();
    int add = 0;
    for (int w = 0; w < wv; ++w) add += wsum[w];
    const int excl = add + v - c;
    if (i < NROWS) {
        if (y < 12) mrank[(size_t)y * NROWS + i] = excl;
        else        offs[i] = excl;
    }
    if (tid == 255) {
        const int tot = wsum[0] + wsum[1] + wsum[2] + wsum[3];
        if (y < 12) msum[y * 256 + blockIdx.x] = tot;
        else        bsum[blockIdx.x] = tot;
    }
}

__global__ __launch_bounds__(256)
void pscan2(const int* __restrict__ msum, const int* __restrict__ bsum,
            int* __restrict__ mbpre, int* __restrict__ bpre,
            int* __restrict__ Ecnt)
{
    __shared__ int wsum[4];
    const int y = blockIdx.x;
    const int tid = threadIdx.x, lane = tid & 63, wv = tid >> 6;
    const int c = (tid < NB) ? ((y < 12) ? msum[y * 256 + tid] : bsum[tid]) : 0;
    int v = c;
    #pragma unroll
    for (int off = 1; off < 64; off <<= 1) {
        const int t = __shfl_up(v, off);
        if (lane >= off) v += t;
    }
    if (lane == 63) wsum[wv] = v;
    __syncthreads();
    int add = 0;
    for (int w = 0; w < wv; ++w) add += wsum[w];
    if (tid < NB) {
        if (y < 12) mbpre[y * 256 + tid] = add + v - c;
        else        bpre[tid] = add + v - c;
    }
    if (tid == 0 && y < 12)
        Ecnt[y] = wsum[0] + wsum[1] + wsum[2] + wsum[3];
}

__global__ __launch_bounds__(256)
void pscan3(const int* __restrict__ mark, int* __restrict__ mrank,
            const int* __restrict__ mbpre, int* __restrict__ live,
            int* __restrict__ offs, const int* __restrict__ bpre,
            const int* __restrict__ countsA, int* __restrict__ cursorA,
            int* __restrict__ cursorB, int* __restrict__ mid)
{
    const int i = blockIdx.x * 256 + threadIdx.x;
    const int y = blockIdx.y;
    if (y < 12) {
        if (i >= NROWS) return;
        const size_t o = (size_t)y * NROWS + i;
        const int rk = mrank[o] + mbpre[y * 256 + blockIdx.x];
        mrank[o] = rk;
        if (mark[o]) live[(size_t)y * NROWS + rk] = i;
    } else {
        if (i < NROWS) {
            const int v = offs[i] + bpre[blockIdx.x];
            offs[i] = v;
            cursorA[i] = v;
            const int m = v + countsA[i];
            mid[i] = m;
            cursorB[i] = m;
        }
        if (i == 0) offs[NROWS] = 12 * NROWS;
    }
}

__global__ __launch_bounds__(256)
void fill_kernel(const int* __restrict__ pidx, const int* __restrict__ sidx,
                 const int* __restrict__ nhp, const int* __restrict__ nhs,
                 const int* __restrict__ mrank,
                 int* __restrict__ cursorA, int* __restrict__ cursorB,
                 int* __restrict__ entries)
{
    const int i = blockIdx.x * 256 + threadIdx.x;
    if (i >= NROWS) return;
    const int s = blockIdx.y;
    const int k = s >> 1, dir = s & 1;
    const int* scp = (dir ? pidx : sidx) + k * NROWS;
    const int* gp  = (dir ? nhs  : nhp)  + k * NROWS;
    const int dst = scp[i];
    const int pos = (s < 6) ? atomicAdd(&cursorA[dst], 1)
                            : atomicAdd(&cursorB[dst], 1);
    entries[pos] = (s << 16) | mrank[(size_t)s * NROWS + gp[i]];
}

// ---------------------------------------------------------------------------
// combine (r13): prefetch-pipelined gather over compacted slots.
// ---------------------------------------------------------------------------
#define PF 20
template<int FIRST, int LAST>
__global__ __launch_bounds__(256)
void combine_f16(const _Float16* __restrict__ YC, _Float16* __restrict__ TEMP16,
                 const _Float16* __restrict__ YB,
                 const int* __restrict__ offsets, const int* __restrict__ mid,
                 const int* __restrict__ entries,
                 int c0, int half,
                 const float* __restrict__ gw, const float* __restrict__ gb,
                 _Float16* __restrict__ Hh)
{
    const int lane = threadIdx.x & 63;
    const int wv   = threadIdx.x >> 6;
    const int r    = blockIdx.x * 4 + wv;
    if (r >= NROWS) return;
    const size_t rowoff = (size_t)r * DIM + lane * 4;

    const f16x4 ivv = FIRST ? *(const f16x4*)(YC + rowoff)
                            : *(const f16x4*)(TEMP16 + rowoff);
    float4 acc;
    acc.x = (float)ivv[0]; acc.y = (float)ivv[1];
    acc.z = (float)ivv[2]; acc.w = (float)ivv[3];

    int e0, e1;
    if (half == 0)      { e0 = offsets[r]; e1 = mid[r]; }
    else if (half == 1) { e0 = mid[r];     e1 = offsets[r + 1]; }
    else                { e0 = offsets[r]; e1 = offsets[r + 1]; }

    const int n  = e1 - e0;
    const int nf = n < PF ? n : PF;
    f16x4 buf[PF];
    #pragma unroll
    for (int t = 0; t < PF; ++t) {
        if (t < nf) {
            const int ent = entries[e0 + t];
            buf[t] = *(const f16x4*)(YB + (size_t)((ent >> 16) - c0) * EMAXND
                                     + (size_t)(ent & 0xFFFF) * DIM + lane * 4);
        }
    }
    #pragma unroll
    for (int t = 0; t < PF; ++t) {
        if (t < nf) {
            acc.x += (float)buf[t][0]; acc.y += (float)buf[t][1];
            acc.z += (float)buf[t][2]; acc.w += (float)buf[t][3];
        }
    }
    for (int e = e0 + nf; e < e1; ++e) {
        const int ent = entries[e];
        const f16x4 yv = *(const f16x4*)(YB + (size_t)((ent >> 16) - c0) * EMAXND
                                         + (size_t)(ent & 0xFFFF) * DIM + lane * 4);
        acc.x += (float)yv[0]; acc.y += (float)yv[1];
        acc.z += (float)yv[2]; acc.w += (float)yv[3];
    }

    if (LAST) {
        float s  = acc.x + acc.y + acc.z + acc.w;
        float ss = acc.x * acc.x + acc.y * acc.y + acc.z * acc.z + acc.w * acc.w;
        #pragma unroll
        for (int off = 32; off >= 1; off >>= 1) {
            s  += __shfl_xor(s, off);
            ss += __shfl_xor(ss, off);
        }
        const float m   = s * (1.0f / DIM);
        const float var = ss * (1.0f / DIM) - m * m;
        const float inv = rsqrtf(var + EPSV);
        const float4 wv4 = *(const float4*)(gw + lane * 4);
        const float4 bv4 = *(const float4*)(gb + lane * 4);
        f16x4 o;
        o[0] = (_Float16)fmaxf((acc.x - m) * inv * wv4.x + bv4.x, 0.f);
        o[1] = (_Float16)fmaxf((acc.y - m) * inv * wv4.y + bv4.y, 0.f);
        o[2] = (_Float16)fmaxf((acc.z - m) * inv * wv4.z + bv4.z, 0.f);
        o[3] = (_Float16)fmaxf((acc.w - m) * inv * wv4.w + bv4.w, 0.f);
        *(f16x4*)(Hh + rowoff) = o;
    } else {
        f16x4 o;
        o[0] = (_Float16)acc.x; o[1] = (_Float16)acc.y;
        o[2] = (_Float16)acc.z; o[3] = (_Float16)acc.w;
        *(f16x4*)(TEMP16 + rowoff) = o;
    }
}

// ---------------------------------------------------------------------------
extern "C" void kernel_launch(void* const* d_in, const int* in_sizes, int n_in,
                              void* d_out, int out_size, void* d_ws, size_t ws_size,
                              hipStream_t stream)
{
    const float* lane   = (const float*)d_in[0];
    const float* W_ctr  = (const float*)d_in[1];
    const float* norm_w = (const float*)d_in[2];
    const float* norm_b = (const float*)d_in[3];
    const float* W_ctr2 = (const float*)d_in[4];
    const float* c2w    = (const float*)d_in[5];
    const float* c2b    = (const float*)d_in[6];
    const float* W_pre  = (const float*)d_in[7];
    const float* W_suc  = (const float*)d_in[8];
    const int*   pidx   = (const int*)d_in[9];
    const int*   sidx   = (const int*)d_in[10];
    const int*   nhp    = (const int*)d_in[11];
    const int*   nhs    = (const int*)d_in[12];

    float* X = (float*)d_out;
    _Float16* YC = (_Float16*)d_out;          // ctr slot lives in d_out

    // ---- workspace layout ----
    char* p = (char*)d_ws;
    int* counts  = (int*)p; p += (size_t)NROWS * 4;
    int* countsA = (int*)p; p += (size_t)NROWS * 4;
    int* offsets = (int*)p; p += (size_t)(NROWS + 4) * 4;
    int* mid     = (int*)p; p += (size_t)NROWS * 4;
    int* cursorA = (int*)p; p += (size_t)NROWS * 4;
    int* cursorB = (int*)p; p += (size_t)NROWS * 4;
    int* bsum    = (int*)p; p += 256 * 4;
    int* bpre    = (int*)p; p += 256 * 4;
    int* msum    = (int*)p; p += 12 * 256 * 4;
    int* mbpre   = (int*)p; p += 12 * 256 * 4;
    int* Ecnt    = (int*)p; p += 16 * 4;
    int* entries = (int*)p; p += (size_t)12 * NROWS * 4;
    int* LIVE    = (int*)p; p += (size_t)12 * NROWS * 4;
    p = (char*)(((uintptr_t)p + 15) & ~(uintptr_t)15);
    _Float16* Xh = (_Float16*)p; p += ND * 2;
    _Float16* Hh = (_Float16*)p; p += ND * 2;
    _Float16* WH = (_Float16*)p; p += (size_t)56 * DIM * DIM * 2;
    p = (char*)(((uintptr_t)p + 255) & ~(uintptr_t)255);
    char* area = p;

    const size_t areaB = ws_size - (size_t)(area - (char*)d_ws);
    const size_t slotb = EMAXND * 2;
    int CH;
    _Float16 *T16, *YBUF;
    if (areaB >= 12 * slotb) {
        CH = 12;
        YBUF = (_Float16*)area;
        T16 = Hh;
    } else {
        CH = 6;
        T16 = (_Float16*)area;
        YBUF = T16 + ND;
    }

    int* mark  = (int*)area;                  // prep-only aliases
    int* mrank = mark + (size_t)12 * NROWS;

    const dim3 blk(256);
    const int  gnBlocks = (NROWS + 3) / 4;

    // one-time prep
    cvt_init<<<16084, blk, 0, stream>>>(lane, Xh, W_ctr, W_ctr2, W_pre, W_suc, WH);
    hipMemsetAsync(counts, 0, 2 * NROWS * sizeof(int), stream);
    hipMemsetAsync(mark, 0, (size_t)12 * NROWS * sizeof(int), stream);
    markcount<<<dim3(NB, 12), blk, 0, stream>>>(pidx, sidx, nhp, nhs,
                                                mark, counts, countsA);
    pscan1<<<dim3(NB, 13), blk, 0, stream>>>(mark, counts, mrank, msum, offsets, bsum);
    pscan2<<<13, blk, 0, stream>>>(msum, bsum, mbpre, bpre, Ecnt);
    pscan3<<<dim3(NB, 13), blk, 0, stream>>>(mark, mrank, mbpre, LIVE,
                                             offsets, bpre, countsA,
                                             cursorA, cursorB, mid);
    fill_kernel<<<dim3(NB, 12), blk, 0, stream>>>(pidx, sidx, nhp, nhs, mrank,
                                                  cursorA, cursorB, entries);

    for (int i = 0; i < ROUNDS; ++i) {
        if (CH == 12) {
            const int nwg = 391 * 2 * 13;
            gemm_p<<<dim3(nwg), blk, 0, stream>>>(Xh, WH, 48 + i, i * 12 - 1,
                                                  13, YC, YBUF, 1, nwg,
                                                  LIVE, Ecnt, -1);
            combine_f16<1, 1><<<gnBlocks, blk, 0, stream>>>(YC, T16, YBUF,
                offsets, mid, entries, 0, -1,
                norm_w + i * DIM, norm_b + i * DIM, Hh);
        } else {
            for (int c0 = 0; c0 < 12; c0 += 6) {
                const bool first = (c0 == 0);
                const int ctr0  = first ? 1 : 0;
                const int slots = 6 + ctr0;
                const int nwg   = 391 * 2 * slots;
                gemm_p<<<dim3(nwg), blk, 0, stream>>>(
                    Xh, WH, first ? (48 + i) : (i * 12 + c0), i * 12 + c0 - ctr0,
                    slots, YC, YBUF, ctr0, nwg, LIVE, Ecnt, c0 - ctr0);
                if (first)
                    combine_f16<1, 0><<<gnBlocks, blk, 0, stream>>>(YC, T16, YBUF,
                        offsets, mid, entries, c0, 0,
                        norm_w + i * DIM, norm_b + i * DIM, Hh);
                else
                    combine_f16<0, 1><<<gnBlocks, blk, 0, stream>>>(YC, T16, YBUF,
                        offsets, mid, entries, c0, 1,
                        norm_w + i * DIM, norm_b + i * DIM, Hh);
            }
        }
        gemm_gn<<<391, 512, 0, stream>>>(Hh, WH, 52 + i, c2w + i * DIM,
                                         c2b + i * DIM, X, Xh,
                                         (i == ROUNDS - 1) ? 1 : 0);
    }
}